// Round 8
// baseline (144.462 us; speedup 1.0000x reference)
//
#include <hip/hip_runtime.h>
#include <math.h>

// EUNN layer, H=1024: 16 steps of (even + odd) pairwise complex rotations + final phase.
// v8 = v7 LDS-resident-coeff structure with the three diagnosed fixes:
//   1. f32 coeffs (v6/v7's f16 cvts added ~40% VALU work: 23us -> 32us busy).
//   2. Ping-pong 32KB halves (2 steps each): stage(g+1) issues before compute(g),
//      one barrier per 2 steps; staged loads get >=2 steps of compute to land.
//   3. __launch_bounds__(512,2): v7's (512,4) made the allocator squeeze to 64 VGPR
//      and spill the row state (+28 MB WRITE_SIZE). Live set ~90 VGPR <= 128 keeps
//      2 blocks/CU (LDS-limited) = 4 waves/SIMD.
// Also: coeff shfl for the odd boundary replaced by a direct LDS read — pair 8l-1's
// (ct,st) is at O-slot lane (l+63)&63, which for lane 0 wraps to pair 511 = identity pad.
//
// ws layout: f4 coeff_t[16][2][512] (16B each), slot k = (j&7)*64 + (j>>3) for pair j
//   (phase 0 = even pairs 0..511; phase 1 = odd pairs 0..510 + identity pad 511)
// omega: f4 (c,s,c,s) per 2 elements, transposed the same way, at float offset 65536.

typedef float f4 __attribute__((ext_vector_type(4)));
typedef float f2 __attribute__((ext_vector_type(2)));

#define OMCS_OFF 65536

__global__ __launch_bounds__(256) void eunn_precompute(
    const float* __restrict__ omega, const float* __restrict__ et,
    const float* __restrict__ ot, const float* __restrict__ ep,
    const float* __restrict__ op, float* __restrict__ ws) {
  int tid = blockIdx.x * 256 + threadIdx.x;
  if (tid < 16384) {
    int s = tid >> 10, k = tid & 1023;
    int phase = k >> 9, j = k & 511;
    float ct, st, cp, sp;
    if (phase == 0) {
      sincosf(et[s * 512 + j], &st, &ct);
      sincosf(ep[s * 512 + j], &sp, &cp);
    } else if (j < 511) {
      sincosf(ot[s * 511 + j], &st, &ct);
      sincosf(op[s * 511 + j], &sp, &cp);
    } else {  // identity pad pair (elements 1023/1024)
      ct = 1.f; st = 0.f; cp = 0.f; sp = 1.f;
    }
    // transposed slot: lane = j>>3 owns pair j as its (j&7)-th register
    ((f4*)ws)[s * 1024 + phase * 512 + (j & 7) * 64 + (j >> 3)] =
        (f4){ct, st, cp, sp};
  } else if (tid < 16896) {
    int m = tid - 16384;  // f4 index covering elements 2m, 2m+1
    float s0, c0, s1, c1;
    sincosf(omega[2 * m], &s0, &c0);
    sincosf(omega[2 * m + 1], &s1, &c1);
    ((f4*)(ws + OMCS_OFF))[(m & 7) * 64 + (m >> 3)] = (f4){c0, s0, c1, s1};
  }
}

// One wave owns ONE row; lane l owns elements 16l..16l+15 (8 even pairs).
// Even rotations register-local; odd rotations register-local except one
// boundary pair per lane (intra-wave shfl for the data, LDS read for the coeff).
__global__ __launch_bounds__(512, 2) void eunn_main(
    const float* __restrict__ x, float* __restrict__ out,
    const float* __restrict__ ws) {
  const int lane = threadIdx.x & 63;
  const int wid = blockIdx.x * 8 + (threadIdx.x >> 6);

  __shared__ __attribute__((aligned(16))) f4 lds[4096];  // 2 x 32 KB halves

  // ---- stage group 0 (steps 0,1 -> half 0): 512 threads x 16 B x 4 rounds ----
  {
    const char* src = (const char*)ws + threadIdx.x * 16;
    char* dst = (char*)lds + threadIdx.x * 16;
#pragma unroll
    for (int r = 0; r < 4; ++r) {
      __builtin_amdgcn_global_load_lds(
          (const __attribute__((address_space(1))) void*)(src + r * 8192),
          (__attribute__((address_space(3))) void*)(dst + r * 8192), 16, 0, 0);
    }
  }

  // e[p] = (re[16l+2p], im[16l+2p], re[16l+2p+1], im[16l+2p+1])
  f4 e[8];
  {
    const f4* xr = (const f4*)(x + (size_t)wid * 2048) + lane * 8;
#pragma unroll
    for (int p = 0; p < 8; ++p) e[p] = xr[p];
  }

  __syncthreads();  // staging of group 0 complete

#pragma unroll 1
  for (int g = 0; g < 8; ++g) {
    // ---- stage next group into the other half (lands during this group) ----
    if (g < 7) {
      const char* src = (const char*)ws + (g + 1) * 32768 + threadIdx.x * 16;
      char* dst = (char*)lds + ((g + 1) & 1) * 32768 + threadIdx.x * 16;
#pragma unroll
      for (int r = 0; r < 4; ++r) {
        __builtin_amdgcn_global_load_lds(
            (const __attribute__((address_space(1))) void*)(src + r * 8192),
            (__attribute__((address_space(3))) void*)(dst + r * 8192), 16, 0,
            0);
      }
    }
    const f4* B = lds + (g & 1) * 2048;
#pragma unroll
    for (int k = 0; k < 2; ++k) {
      const f4* L = B + k * 1024;
      // ---- even coeffs: lane-contiguous ds_read_b128 ----
      f4 E[8];
#pragma unroll
      for (int p = 0; p < 8; ++p) E[p] = L[p * 64 + lane];
      // ---- even rotation: pair j=8l+p couples (e.x,e.y) and (e.z,e.w) ----
#pragma unroll
      for (int p = 0; p < 8; ++p) {
        f4 c = E[p];
        f4 v = e[p];
        float t0 = c.x * v.x - c.y * v.z;
        float t1 = c.x * v.y - c.y * v.w;
        e[p] = (f4){c.w * t0 - c.z * t1, c.z * t0 + c.w * t1,
                    c.y * v.x + c.x * v.z, c.y * v.y + c.x * v.w};
      }
      // ---- odd coeffs ----
      f4 O[8];
#pragma unroll
      for (int p = 0; p < 8; ++p) O[p] = L[512 + p * 64 + lane];
      // neighbor pair (8l-1)'s (ct,st): direct LDS read at lane-1 (mod 64);
      // lane 0 wraps to pair 511 = identity pad (ct=1, st=0).
      f2 cm = ((const f2*)L)[(512 + 7 * 64 + ((lane + 63) & 63)) * 2];
      // ---- odd rotation: pair j couples elements 2j+1, 2j+2 ----
      {
        float upx = __shfl_down(e[0].x, 1, 64);  // elem 16l+16 (pre)
        float upy = __shfl_down(e[0].y, 1, 64);
        float dnz = __shfl_up(e[7].z, 1, 64);    // elem 16l-1 (pre)
        float dnw = __shfl_up(e[7].w, 1, 64);
        // element 16l = second half of pair 8l-1 (stm=0 at lane 0 kills dn*)
        float nx = cm.y * dnz + cm.x * e[0].x;
        float ny = cm.y * dnw + cm.x * e[0].y;
        e[0].x = nx;
        e[0].y = ny;
        // interior odd pairs j=8l+p, p=0..6
#pragma unroll
        for (int p = 0; p < 7; ++p) {
          f4 c = O[p];
          float e0r = e[p].z, e0i = e[p].w;
          float e1r = e[p + 1].x, e1i = e[p + 1].y;
          float t0 = c.x * e0r - c.y * e1r;
          float t1 = c.x * e0i - c.y * e1i;
          e[p].z = c.w * t0 - c.z * t1;
          e[p].w = c.z * t0 + c.w * t1;
          e[p + 1].x = c.y * e0r + c.x * e1r;
          e[p + 1].y = c.y * e0i + c.x * e1i;
        }
        // boundary pair j=8l+7 (second element in lane l+1; lane 63 = identity,
        // whose ct=1/st=0 makes upx/upy don't-cares)
        {
          f4 c = O[7];
          float e0r = e[7].z, e0i = e[7].w;
          float t0 = c.x * e0r - c.y * upx;
          float t1 = c.x * e0i - c.y * upy;
          e[7].z = c.w * t0 - c.z * t1;
          e[7].w = c.z * t0 + c.w * t1;
        }
      }
    }
    __syncthreads();  // group done; staged loads for g+1 also drained here
  }

  // ---- final diagonal phase + store ----
  const f4* om4 = (const f4*)(ws + OMCS_OFF) + lane;  // (c,s,c,s), + p*64
  {
    f4* outr = (f4*)(out + (size_t)wid * 2048) + lane * 8;
#pragma unroll
    for (int p = 0; p < 8; ++p) {
      f4 v = e[p];
      f4 w = om4[p * 64];
      outr[p] = (f4){v.x * w.x - v.y * w.y, v.x * w.y + v.y * w.x,
                     v.z * w.z - v.w * w.w, v.z * w.w + v.w * w.z};
    }
  }
}

extern "C" void kernel_launch(void* const* d_in, const int* in_sizes, int n_in,
                              void* d_out, int out_size, void* d_ws, size_t ws_size,
                              hipStream_t stream) {
  const float* x     = (const float*)d_in[0];  // (4096,1024,2)
  const float* omega = (const float*)d_in[1];  // (1024,)
  const float* et    = (const float*)d_in[2];  // (16,512)
  const float* ot    = (const float*)d_in[3];  // (16,511)
  const float* ep    = (const float*)d_in[4];  // (16,512)
  const float* op    = (const float*)d_in[5];  // (16,511)
  float* out = (float*)d_out;
  float* ws  = (float*)d_ws;

  // 16896 jobs: 16x1024 coeff quads + 512 omega f4 entries
  eunn_precompute<<<dim3(66), dim3(256), 0, stream>>>(omega, et, ot, ep, op, ws);

  // 1 row/wave: 4096 waves, 8 waves/block -> 512 blocks, 2 blocks/CU, 4 waves/SIMD
  eunn_main<<<dim3(512), dim3(512), 0, stream>>>(x, out, ws);
}